// Round 1
// baseline (2325.991 us; speedup 1.0000x reference)
//
#include <hip/hip_runtime.h>

#define NN 100000
#define NE 1600000
#define D1 128
#define D2 64
#define BN_EPS 1e-5f

// ---------------- degree count (atomic, from dst) ----------------
__global__ __launch_bounds__(256) void deg_count_k(const int* __restrict__ dst,
                                                   float* __restrict__ deg) {
    int i = blockIdx.x * 256 + threadIdx.x;
    if (i < NE) atomicAdd(&deg[dst[i]], 1.0f);
}

// ---------------- dis = rsqrt(deg+1) ----------------
__global__ __launch_bounds__(256) void make_dis_k(const float* __restrict__ deg,
                                                  float* __restrict__ dis) {
    int i = blockIdx.x * 256 + threadIdx.x;
    if (i < NN) dis[i] = rsqrtf(deg[i] + 1.0f);
}

// ---------------- GEMM: Y[NN,OUT] = X[NN,128] @ W[128,OUT] ----------------
// W staged in LDS (64KB for OUT=128). 32 rows per block, 256 threads.
template<int OUT>
__global__ __launch_bounds__(256) void gemm_k128(const float* __restrict__ X,
                                                 const float* __restrict__ W,
                                                 float* __restrict__ Y) {
    __shared__ float sW[128 * OUT];
    for (int i = threadIdx.x; i < 128 * OUT; i += 256) sW[i] = W[i];
    __syncthreads();
    constexpr int CG = OUT / 4;      // col groups of 4 (32 or 16)
    constexpr int RG = 256 / CG;     // row groups (8 or 16)
    constexpr int R  = 32 / RG;      // rows per thread (4 or 2)
    const int cg = threadIdx.x % CG;
    const int rg = threadIdx.x / CG;
    const int row0 = blockIdx.x * 32 + rg * R;
    float acc[R][4];
    #pragma unroll
    for (int rr = 0; rr < R; ++rr)
        acc[rr][0] = acc[rr][1] = acc[rr][2] = acc[rr][3] = 0.f;
    const float* xp[R];
    #pragma unroll
    for (int rr = 0; rr < R; ++rr) xp[rr] = X + (size_t)(row0 + rr) * 128;

    for (int k = 0; k < 128; k += 4) {
        float4 xv[R];
        #pragma unroll
        for (int rr = 0; rr < R; ++rr) xv[rr] = *(const float4*)(xp[rr] + k);
        #pragma unroll
        for (int kk = 0; kk < 4; ++kk) {
            float4 w = *(const float4*)&sW[(k + kk) * OUT + cg * 4];
            #pragma unroll
            for (int rr = 0; rr < R; ++rr) {
                float xs = ((const float*)&xv[rr])[kk];
                acc[rr][0] = fmaf(xs, w.x, acc[rr][0]);
                acc[rr][1] = fmaf(xs, w.y, acc[rr][1]);
                acc[rr][2] = fmaf(xs, w.z, acc[rr][2]);
                acc[rr][3] = fmaf(xs, w.w, acc[rr][3]);
            }
        }
    }
    #pragma unroll
    for (int rr = 0; rr < R; ++rr) {
        int r = row0 + rr;
        if (r < NN)
            *(float4*)&Y[(size_t)r * OUT + cg * 4] =
                make_float4(acc[rr][0], acc[rr][1], acc[rr][2], acc[rr][3]);
    }
}

// ---------------- edge scatter: agg[dst] += xw[src]*norm (atomics) ----------------
// one wave per edge; lanes split the feature dim
template<int DIM>
__global__ __launch_bounds__(256) void scatter_k(const int* __restrict__ src,
                                                 const int* __restrict__ dst,
                                                 const float* __restrict__ dis,
                                                 const float* __restrict__ xw,
                                                 float* __restrict__ agg) {
    int wid = (blockIdx.x * 256 + threadIdx.x) >> 6;
    int lane = threadIdx.x & 63;
    if (wid >= NE) return;
    int s = src[wid], d = dst[wid];
    float nrm = dis[s] * dis[d];
    if constexpr (DIM == 128) {
        float2 v = *(const float2*)&xw[(size_t)s * 128 + lane * 2];
        float* ap = &agg[(size_t)d * 128 + lane * 2];
        atomicAdd(ap, v.x * nrm);
        atomicAdd(ap + 1, v.y * nrm);
    } else {
        float v = xw[(size_t)s * 64 + lane];
        atomicAdd(&agg[(size_t)d * 64 + lane], v * nrm);
    }
}

// ---------------- self-loop + bias, fused BN partial stats ----------------
template<int DIM>
__global__ __launch_bounds__(256) void self_stats_k(const float* __restrict__ xw,
                                                    const float* __restrict__ dis,
                                                    const float* __restrict__ b,
                                                    float* __restrict__ agg,
                                                    float* __restrict__ sums,
                                                    float* __restrict__ ssq) {
    const int col = threadIdx.x & (DIM - 1);
    const float bc = b[col];
    float lsum = 0.f, lsq = 0.f;
    const unsigned total = (unsigned)NN * DIM;
    for (unsigned idx = blockIdx.x * 256u + threadIdx.x; idx < total;
         idx += gridDim.x * 256u) {
        unsigned node = idx / DIM;  // power-of-2 shift
        float ds = dis[node];
        float v = agg[idx] + xw[idx] * (ds * ds) + bc;
        agg[idx] = v;
        lsum += v;
        lsq = fmaf(v, v, lsq);
    }
    __shared__ float sb[256];
    sb[threadIdx.x] = lsum;
    __syncthreads();
    if (threadIdx.x < DIM) {
        float t = lsum;
        for (int o = DIM; o < 256; o += DIM) t += sb[threadIdx.x + o];
        atomicAdd(&sums[col], t);
    }
    __syncthreads();
    sb[threadIdx.x] = lsq;
    __syncthreads();
    if (threadIdx.x < DIM) {
        float t = lsq;
        for (int o = DIM; o < 256; o += DIM) t += sb[threadIdx.x + o];
        atomicAdd(&ssq[col], t);
    }
}

// ---------------- BN apply + ReLU (in place) ----------------
template<int DIM>
__global__ __launch_bounds__(256) void bn_relu_k(float* __restrict__ h,
                                                 const float* __restrict__ sums,
                                                 const float* __restrict__ ssq,
                                                 const float* __restrict__ g,
                                                 const float* __restrict__ beta) {
    unsigned idx = blockIdx.x * 256u + threadIdx.x;
    const unsigned total = (unsigned)NN * DIM;
    if (idx >= total) return;
    int col = idx & (DIM - 1);
    float m = sums[col] * (1.0f / NN);
    float var = ssq[col] * (1.0f / NN) - m * m;
    float inv = rsqrtf(var + BN_EPS);
    float v = (h[idx] - m) * inv * g[col] + beta[col];
    h[idx] = fmaxf(v, 0.f);
}

// ---------------- final: out = h2 @ Wf + bf ----------------
__global__ __launch_bounds__(256) void final_k(const float* __restrict__ h,
                                               const float* __restrict__ Wf,
                                               const float* __restrict__ bf,
                                               float* __restrict__ out) {
    int wid = (blockIdx.x * 256 + threadIdx.x) >> 6;
    int lane = threadIdx.x & 63;
    if (wid >= NN) return;
    float v = h[(size_t)wid * 64 + lane] * Wf[lane];
    #pragma unroll
    for (int o = 32; o > 0; o >>= 1) v += __shfl_down(v, o);
    if (lane == 0) out[wid] = v + bf[0];
}

extern "C" void kernel_launch(void* const* d_in, const int* in_sizes, int n_in,
                              void* d_out, int out_size, void* d_ws, size_t ws_size,
                              hipStream_t stream) {
    const float* x   = (const float*)d_in[0];
    const int*   ei  = (const int*)d_in[1];
    const int*   src = ei;            // edge_index[0]
    const int*   dst = ei + NE;       // edge_index[1]
    const float* W1  = (const float*)d_in[2];
    const float* b1  = (const float*)d_in[3];
    const float* g1  = (const float*)d_in[4];
    const float* be1 = (const float*)d_in[5];
    const float* W2  = (const float*)d_in[6];
    const float* b2  = (const float*)d_in[7];
    const float* g2  = (const float*)d_in[8];
    const float* be2 = (const float*)d_in[9];
    const float* Wf  = (const float*)d_in[10];
    const float* bf  = (const float*)d_in[11];
    float* out = (float*)d_out;

    float* ws    = (float*)d_ws;
    float* xw    = ws;                        // NN*128 floats (51.2MB), reused as xw2
    float* agg1  = xw   + (size_t)NN * D1;    // NN*128
    float* agg2  = agg1 + (size_t)NN * D1;    // NN*64
    float* deg   = agg2 + (size_t)NN * D2;    // NN
    float* dis   = deg  + NN;                 // NN
    float* sums1 = dis  + NN;                 // 128
    float* ssq1  = sums1 + D1;                // 128
    float* sums2 = ssq1  + D1;                // 64
    float* ssq2  = sums2 + D2;                // 64

    // zero accumulators (poisoned 0xAA otherwise; must re-init every call)
    hipMemsetAsync(agg1, 0, sizeof(float) * ((size_t)NN * D1 + (size_t)NN * D2), stream);
    hipMemsetAsync(deg, 0, sizeof(float) * NN, stream);
    hipMemsetAsync(sums1, 0, sizeof(float) * (2 * D1 + 2 * D2), stream);

    deg_count_k<<<(NE + 255) / 256, 256, 0, stream>>>(dst, deg);
    make_dis_k<<<(NN + 255) / 256, 256, 0, stream>>>(deg, dis);

    // layer 1
    gemm_k128<128><<<NN / 32, 256, 0, stream>>>(x, W1, xw);
    scatter_k<128><<<NE / 4, 256, 0, stream>>>(src, dst, dis, xw, agg1);
    self_stats_k<128><<<1024, 256, 0, stream>>>(xw, dis, b1, agg1, sums1, ssq1);
    bn_relu_k<128><<<(NN * D1 + 255) / 256, 256, 0, stream>>>(agg1, sums1, ssq1, g1, be1);

    // layer 2 (xw buffer reused for xw2 = h1 @ W2)
    gemm_k128<64><<<NN / 32, 256, 0, stream>>>(agg1, W2, xw);
    scatter_k<64><<<NE / 4, 256, 0, stream>>>(src, dst, dis, xw, agg2);
    self_stats_k<64><<<1024, 256, 0, stream>>>(xw, dis, b2, agg2, sums2, ssq2);
    bn_relu_k<64><<<(NN * D2 + 255) / 256, 256, 0, stream>>>(agg2, sums2, ssq2, g2, be2);

    // final projection
    final_k<<<(NN * 64 + 255) / 256, 256, 0, stream>>>(agg2, Wf, bf, out);
}

// Round 2
// 946.462 us; speedup vs baseline: 2.4576x; 2.4576x over previous
//
#include <hip/hip_runtime.h>

#define NN 100000
#define NE 1600000
#define D1 128
#define D2 64
#define BN_EPS 1e-5f
#define SCAN_CHUNK 512
#define NB_SCAN ((NN + SCAN_CHUNK - 1) / SCAN_CHUNK)   // 196

// ---------------- degree count (int atomics, from dst) ----------------
__global__ __launch_bounds__(256) void cnt_k(const int* __restrict__ dst,
                                             int* __restrict__ cnt) {
    int i = blockIdx.x * 256 + threadIdx.x;
    if (i < NE) atomicAdd(&cnt[dst[i]], 1);
}

// ---------------- dis = rsqrt(cnt+1) ----------------
__global__ __launch_bounds__(256) void make_dis_k(const int* __restrict__ cnt,
                                                  float* __restrict__ dis) {
    int i = blockIdx.x * 256 + threadIdx.x;
    if (i < NN) dis[i] = rsqrtf((float)cnt[i] + 1.0f);
}

// ---------------- prefix scan (3 kernels) ----------------
__global__ __launch_bounds__(SCAN_CHUNK) void scan1_k(const int* __restrict__ cnt,
                                                      int* __restrict__ rowptr,
                                                      int* __restrict__ bsum) {
    __shared__ int sh[SCAN_CHUNK];
    int tid = threadIdx.x;
    int g = blockIdx.x * SCAN_CHUNK + tid;
    int v = (g < NN) ? cnt[g] : 0;
    sh[tid] = v;
    __syncthreads();
    for (int o = 1; o < SCAN_CHUNK; o <<= 1) {
        int t = (tid >= o) ? sh[tid - o] : 0;
        __syncthreads();
        sh[tid] += t;
        __syncthreads();
    }
    if (g < NN) rowptr[g] = sh[tid] - v;  // exclusive within block
    if (tid == SCAN_CHUNK - 1) bsum[blockIdx.x] = sh[tid];
}

__global__ void scan2_k(int* __restrict__ bsum) {
    if (threadIdx.x == 0 && blockIdx.x == 0) {
        int a = 0;
        for (int i = 0; i < NB_SCAN; ++i) { int t = bsum[i]; bsum[i] = a; a += t; }
    }
}

__global__ __launch_bounds__(256) void scan3_k(int* __restrict__ rowptr,
                                               const int* __restrict__ bsum) {
    int g = blockIdx.x * 256 + threadIdx.x;
    if (g < NN) rowptr[g] += bsum[g >> 9];
    if (g == 0) rowptr[NN] = NE;
}

// ---------------- CSR fill: slot-atomic per edge ----------------
__global__ __launch_bounds__(256) void fill_k(const int* __restrict__ src,
                                              const int* __restrict__ dst,
                                              const int* __restrict__ rowptr,
                                              int* __restrict__ cur,
                                              int* __restrict__ esrc) {
    int e = blockIdx.x * 256 + threadIdx.x;
    if (e >= NE) return;
    int d = dst[e];
    int p = rowptr[d] + atomicAdd(&cur[d], 1);
    esrc[p] = src[e];
}

// ---------------- GEMM: Y[NN,OUT] = X[NN,128] @ W[128,OUT] ----------------
template<int OUT>
__global__ __launch_bounds__(256) void gemm_k128(const float* __restrict__ X,
                                                 const float* __restrict__ W,
                                                 float* __restrict__ Y) {
    __shared__ float sW[128 * OUT];
    for (int i = threadIdx.x; i < 128 * OUT; i += 256) sW[i] = W[i];
    __syncthreads();
    constexpr int CG = OUT / 4;
    constexpr int RG = 256 / CG;
    constexpr int R  = 32 / RG;
    const int cg = threadIdx.x % CG;
    const int rg = threadIdx.x / CG;
    const int row0 = blockIdx.x * 32 + rg * R;
    float acc[R][4];
    #pragma unroll
    for (int rr = 0; rr < R; ++rr)
        acc[rr][0] = acc[rr][1] = acc[rr][2] = acc[rr][3] = 0.f;
    const float* xp[R];
    #pragma unroll
    for (int rr = 0; rr < R; ++rr) xp[rr] = X + (size_t)(row0 + rr) * 128;

    for (int k = 0; k < 128; k += 4) {
        float4 xv[R];
        #pragma unroll
        for (int rr = 0; rr < R; ++rr) xv[rr] = *(const float4*)(xp[rr] + k);
        #pragma unroll
        for (int kk = 0; kk < 4; ++kk) {
            float4 w = *(const float4*)&sW[(k + kk) * OUT + cg * 4];
            #pragma unroll
            for (int rr = 0; rr < R; ++rr) {
                float xs = ((const float*)&xv[rr])[kk];
                acc[rr][0] = fmaf(xs, w.x, acc[rr][0]);
                acc[rr][1] = fmaf(xs, w.y, acc[rr][1]);
                acc[rr][2] = fmaf(xs, w.z, acc[rr][2]);
                acc[rr][3] = fmaf(xs, w.w, acc[rr][3]);
            }
        }
    }
    #pragma unroll
    for (int rr = 0; rr < R; ++rr) {
        int r = row0 + rr;
        if (r < NN)
            *(float4*)&Y[(size_t)r * OUT + cg * 4] =
                make_float4(acc[rr][0], acc[rr][1], acc[rr][2], acc[rr][3]);
    }
}

// ---------------- fused: CSR gather-aggregate + self-loop + bias + BN partial stats ----------------
// one wave per node (grid-stride); DIM=128: lane owns cols {2l,2l+1}; DIM=64: col l
template<int DIM>
__global__ __launch_bounds__(256) void agg_k(const int* __restrict__ rowptr,
                                             const int* __restrict__ esrc,
                                             const float* __restrict__ dis,
                                             const float* __restrict__ xw,
                                             const float* __restrict__ b,
                                             float* __restrict__ agg,
                                             float* __restrict__ sums,
                                             float* __restrict__ ssq) {
    const int lane = threadIdx.x & 63;
    const int wid = (blockIdx.x * 256 + threadIdx.x) >> 6;
    const int nwaves = gridDim.x * 4;
    float s0 = 0.f, s1 = 0.f, q0 = 0.f, q1 = 0.f;

    if constexpr (DIM == 128) {
        const float bc0 = b[lane * 2], bc1 = b[lane * 2 + 1];
        for (int n = wid; n < NN; n += nwaves) {
            const int beg = rowptr[n], end = rowptr[n + 1];
            const float dn = dis[n];
            float ax = 0.f, ay = 0.f;
            int e = beg;
            for (; e + 4 <= end; e += 4) {
                int i0 = esrc[e], i1 = esrc[e + 1], i2 = esrc[e + 2], i3 = esrc[e + 3];
                float w0 = dis[i0] * dn, w1 = dis[i1] * dn,
                      w2 = dis[i2] * dn, w3 = dis[i3] * dn;
                float2 v0 = *(const float2*)&xw[(size_t)i0 * 128 + lane * 2];
                float2 v1 = *(const float2*)&xw[(size_t)i1 * 128 + lane * 2];
                float2 v2 = *(const float2*)&xw[(size_t)i2 * 128 + lane * 2];
                float2 v3 = *(const float2*)&xw[(size_t)i3 * 128 + lane * 2];
                ax = fmaf(v0.x, w0, ax); ay = fmaf(v0.y, w0, ay);
                ax = fmaf(v1.x, w1, ax); ay = fmaf(v1.y, w1, ay);
                ax = fmaf(v2.x, w2, ax); ay = fmaf(v2.y, w2, ay);
                ax = fmaf(v3.x, w3, ax); ay = fmaf(v3.y, w3, ay);
            }
            for (; e < end; ++e) {
                int s = esrc[e];
                float w = dis[s] * dn;
                float2 v = *(const float2*)&xw[(size_t)s * 128 + lane * 2];
                ax = fmaf(v.x, w, ax); ay = fmaf(v.y, w, ay);
            }
            float sl = dn * dn;  // 1/(deg+1) self-loop norm
            float2 xv = *(const float2*)&xw[(size_t)n * 128 + lane * 2];
            ax = fmaf(xv.x, sl, ax) + bc0;
            ay = fmaf(xv.y, sl, ay) + bc1;
            *(float2*)&agg[(size_t)n * 128 + lane * 2] = make_float2(ax, ay);
            s0 += ax; q0 = fmaf(ax, ax, q0);
            s1 += ay; q1 = fmaf(ay, ay, q1);
        }
    } else {
        const float bc0 = b[lane];
        for (int n = wid; n < NN; n += nwaves) {
            const int beg = rowptr[n], end = rowptr[n + 1];
            const float dn = dis[n];
            float ax = 0.f;
            int e = beg;
            for (; e + 4 <= end; e += 4) {
                int i0 = esrc[e], i1 = esrc[e + 1], i2 = esrc[e + 2], i3 = esrc[e + 3];
                float w0 = dis[i0] * dn, w1 = dis[i1] * dn,
                      w2 = dis[i2] * dn, w3 = dis[i3] * dn;
                ax = fmaf(xw[(size_t)i0 * 64 + lane], w0, ax);
                ax = fmaf(xw[(size_t)i1 * 64 + lane], w1, ax);
                ax = fmaf(xw[(size_t)i2 * 64 + lane], w2, ax);
                ax = fmaf(xw[(size_t)i3 * 64 + lane], w3, ax);
            }
            for (; e < end; ++e) {
                int s = esrc[e];
                ax = fmaf(xw[(size_t)s * 64 + lane], dis[s] * dn, ax);
            }
            ax = fmaf(xw[(size_t)n * 64 + lane], dn * dn, ax) + bc0;
            agg[(size_t)n * 64 + lane] = ax;
            s0 += ax; q0 = fmaf(ax, ax, q0);
        }
    }

    // block-level stats reduce: LDS atomics then one global atomic per column
    __shared__ float ls[2 * DIM];
    if (threadIdx.x < 2 * DIM) ls[threadIdx.x] = 0.f;
    __syncthreads();
    if constexpr (DIM == 128) {
        atomicAdd(&ls[lane * 2], s0);
        atomicAdd(&ls[lane * 2 + 1], s1);
        atomicAdd(&ls[DIM + lane * 2], q0);
        atomicAdd(&ls[DIM + lane * 2 + 1], q1);
    } else {
        atomicAdd(&ls[lane], s0);
        atomicAdd(&ls[DIM + lane], q0);
    }
    __syncthreads();
    if (threadIdx.x < DIM) atomicAdd(&sums[threadIdx.x], ls[threadIdx.x]);
    else if (threadIdx.x < 2 * DIM) atomicAdd(&ssq[threadIdx.x - DIM], ls[threadIdx.x]);
}

// ---------------- BN apply + ReLU (in place) ----------------
template<int DIM>
__global__ __launch_bounds__(256) void bn_relu_k(float* __restrict__ h,
                                                 const float* __restrict__ sums,
                                                 const float* __restrict__ ssq,
                                                 const float* __restrict__ g,
                                                 const float* __restrict__ beta) {
    unsigned idx = blockIdx.x * 256u + threadIdx.x;
    const unsigned total = (unsigned)NN * DIM;
    if (idx >= total) return;
    int col = idx & (DIM - 1);
    float m = sums[col] * (1.0f / NN);
    float var = ssq[col] * (1.0f / NN) - m * m;
    float inv = rsqrtf(var + BN_EPS);
    float v = (h[idx] - m) * inv * g[col] + beta[col];
    h[idx] = fmaxf(v, 0.f);
}

// ---------------- final: out = h2 @ Wf + bf ----------------
__global__ __launch_bounds__(256) void final_k(const float* __restrict__ h,
                                               const float* __restrict__ Wf,
                                               const float* __restrict__ bf,
                                               float* __restrict__ out) {
    int wid = (blockIdx.x * 256 + threadIdx.x) >> 6;
    int lane = threadIdx.x & 63;
    if (wid >= NN) return;
    float v = h[(size_t)wid * 64 + lane] * Wf[lane];
    #pragma unroll
    for (int o = 32; o > 0; o >>= 1) v += __shfl_down(v, o);
    if (lane == 0) out[wid] = v + bf[0];
}

extern "C" void kernel_launch(void* const* d_in, const int* in_sizes, int n_in,
                              void* d_out, int out_size, void* d_ws, size_t ws_size,
                              hipStream_t stream) {
    const float* x   = (const float*)d_in[0];
    const int*   ei  = (const int*)d_in[1];
    const int*   src = ei;
    const int*   dst = ei + NE;
    const float* W1  = (const float*)d_in[2];
    const float* b1  = (const float*)d_in[3];
    const float* g1  = (const float*)d_in[4];
    const float* be1 = (const float*)d_in[5];
    const float* W2  = (const float*)d_in[6];
    const float* b2  = (const float*)d_in[7];
    const float* g2  = (const float*)d_in[8];
    const float* be2 = (const float*)d_in[9];
    const float* Wf  = (const float*)d_in[10];
    const float* bf  = (const float*)d_in[11];
    float* out = (float*)d_out;

    // ---- workspace layout ----
    float* xw    = (float*)d_ws;                 // NN*128 (reused as xw2)
    float* agg1  = xw    + (size_t)NN * D1;      // NN*128
    float* agg2  = agg1  + (size_t)NN * D1;      // NN*64
    float* dis   = agg2  + (size_t)NN * D2;      // NN
    float* sums1 = dis   + NN;                   // 128
    float* ssq1  = sums1 + D1;                   // 128
    float* sums2 = ssq1  + D1;                   // 64
    float* ssq2  = sums2 + D2;                   // 64
    int*   cnt    = (int*)(ssq2 + D2);           // NN
    int*   cur    = cnt + NN;                    // NN
    int*   rowptr = cur + NN;                    // NN+1
    int*   bsum   = rowptr + NN + 1;             // 256 (pad)
    int*   esrc   = bsum + 256;                  // NE

    // zero: cnt+cur (contiguous), stats
    hipMemsetAsync(cnt, 0, sizeof(int) * 2 * NN, stream);
    hipMemsetAsync(sums1, 0, sizeof(float) * (2 * D1 + 2 * D2), stream);

    // ---- CSR build ----
    cnt_k<<<(NE + 255) / 256, 256, 0, stream>>>(dst, cnt);
    make_dis_k<<<(NN + 255) / 256, 256, 0, stream>>>(cnt, dis);
    scan1_k<<<NB_SCAN, SCAN_CHUNK, 0, stream>>>(cnt, rowptr, bsum);
    scan2_k<<<1, 64, 0, stream>>>(bsum);
    scan3_k<<<(NN + 255) / 256, 256, 0, stream>>>(rowptr, bsum);
    fill_k<<<(NE + 255) / 256, 256, 0, stream>>>(src, dst, rowptr, cur, esrc);

    // ---- layer 1 ----
    gemm_k128<128><<<NN / 32, 256, 0, stream>>>(x, W1, xw);
    agg_k<128><<<1024, 256, 0, stream>>>(rowptr, esrc, dis, xw, b1, agg1, sums1, ssq1);
    bn_relu_k<128><<<(NN * D1 + 255) / 256, 256, 0, stream>>>(agg1, sums1, ssq1, g1, be1);

    // ---- layer 2 ----
    gemm_k128<64><<<NN / 32, 256, 0, stream>>>(agg1, W2, xw);
    agg_k<64><<<1024, 256, 0, stream>>>(rowptr, esrc, dis, xw, b2, agg2, sums2, ssq2);
    bn_relu_k<64><<<(NN * D2 + 255) / 256, 256, 0, stream>>>(agg2, sums2, ssq2, g2, be2);

    // ---- final projection ----
    final_k<<<(NN * 64 + 255) / 256, 256, 0, stream>>>(agg2, Wf, bf, out);
}

// Round 3
// 590.325 us; speedup vs baseline: 3.9402x; 1.6033x over previous
//
#include <hip/hip_runtime.h>

#define NN 100000
#define NE 1600000
#define D1 128
#define D2 64
#define BN_EPS 1e-5f
#define SCAN_CHUNK 512
#define NB_SCAN ((NN + SCAN_CHUNK - 1) / SCAN_CHUNK)   // 196

// ---------------- degree count (int atomics, from dst) ----------------
__global__ __launch_bounds__(256) void cnt_k(const int* __restrict__ dst,
                                             int* __restrict__ cnt) {
    int i = blockIdx.x * 256 + threadIdx.x;
    if (i < NE) atomicAdd(&cnt[dst[i]], 1);
}

// ---------------- dis = rsqrt(cnt+1) ----------------
__global__ __launch_bounds__(256) void make_dis_k(const int* __restrict__ cnt,
                                                  float* __restrict__ dis) {
    int i = blockIdx.x * 256 + threadIdx.x;
    if (i < NN) dis[i] = rsqrtf((float)cnt[i] + 1.0f);
}

// ---------------- prefix scan (3 kernels) ----------------
__global__ __launch_bounds__(SCAN_CHUNK) void scan1_k(const int* __restrict__ cnt,
                                                      int* __restrict__ rowptr,
                                                      int* __restrict__ bsum) {
    __shared__ int sh[SCAN_CHUNK];
    int tid = threadIdx.x;
    int g = blockIdx.x * SCAN_CHUNK + tid;
    int v = (g < NN) ? cnt[g] : 0;
    sh[tid] = v;
    __syncthreads();
    for (int o = 1; o < SCAN_CHUNK; o <<= 1) {
        int t = (tid >= o) ? sh[tid - o] : 0;
        __syncthreads();
        sh[tid] += t;
        __syncthreads();
    }
    if (g < NN) rowptr[g] = sh[tid] - v;  // exclusive within block
    if (tid == SCAN_CHUNK - 1) bsum[blockIdx.x] = sh[tid];
}

__global__ void scan2_k(int* __restrict__ bsum) {
    if (threadIdx.x == 0 && blockIdx.x == 0) {
        int a = 0;
        for (int i = 0; i < NB_SCAN; ++i) { int t = bsum[i]; bsum[i] = a; a += t; }
    }
}

__global__ __launch_bounds__(256) void scan3_k(int* __restrict__ rowptr,
                                               const int* __restrict__ bsum) {
    int g = blockIdx.x * 256 + threadIdx.x;
    if (g < NN) rowptr[g] += bsum[g >> 9];
    if (g == 0) rowptr[NN] = NE;
}

// ---------------- CSR fill: slot-atomic per edge ----------------
__global__ __launch_bounds__(256) void fill_k(const int* __restrict__ src,
                                              const int* __restrict__ dst,
                                              const int* __restrict__ rowptr,
                                              int* __restrict__ cur,
                                              int* __restrict__ esrc) {
    int e = blockIdx.x * 256 + threadIdx.x;
    if (e >= NE) return;
    int d = dst[e];
    int p = rowptr[d] + atomicAdd(&cur[d], 1);
    esrc[p] = src[e];
}

// ---------------- BN coefficients: scale = g*rsqrt(var+eps), shift = beta - m*scale ----------------
__global__ void bncoef_k(const float* __restrict__ sums, const float* __restrict__ ssq,
                         const float* __restrict__ g, const float* __restrict__ beta,
                         float* __restrict__ coef, int dim) {
    int c = threadIdx.x;
    if (c >= dim) return;
    float m = sums[c] * (1.0f / NN);
    float var = ssq[c] * (1.0f / NN) - m * m;
    float sc = g[c] * rsqrtf(var + BN_EPS);
    coef[c] = sc;
    coef[dim + c] = beta[c] - m * sc;
}

// ---------------- GEMM: Y[NN,OUT] = f(X)[NN,128] @ W[128,OUT] ----------------
// 64 rows/block, 256 threads, W staged in 32-k chunks (<=16KB LDS).
// FUSE_BN: X element -> relu(x*scale[k]+shift[k]) on load (layer-1 BN fused into layer-2 GEMM).
template<int OUT, bool FUSE_BN>
__global__ __launch_bounds__(256, 3) void gemm_k(const float* __restrict__ X,
                                                 const float* __restrict__ W,
                                                 const float* __restrict__ coef,
                                                 float* __restrict__ Y) {
    constexpr int CG = OUT / 4;      // col groups (32 or 16)
    constexpr int RG = 256 / CG;     // row groups (8 or 16)
    constexpr int R  = 64 / RG;      // rows/thread (8 or 4)
    __shared__ float sW[32 * OUT];
    __shared__ float sc[128], sh[128];
    if constexpr (FUSE_BN) {
        if (threadIdx.x < 128) {
            sc[threadIdx.x] = coef[threadIdx.x];
            sh[threadIdx.x] = coef[128 + threadIdx.x];
        }
    }
    const int cg = threadIdx.x % CG;
    const int rg = threadIdx.x / CG;
    const int row0 = blockIdx.x * 64 + rg * R;
    int rows[R];
    #pragma unroll
    for (int r = 0; r < R; ++r) rows[r] = min(row0 + r, NN - 1);
    float acc[R][4];
    #pragma unroll
    for (int r = 0; r < R; ++r)
        acc[r][0] = acc[r][1] = acc[r][2] = acc[r][3] = 0.f;

    for (int kc = 0; kc < 128; kc += 32) {
        for (int i = threadIdx.x; i < 32 * OUT / 4; i += 256)
            ((float4*)sW)[i] = ((const float4*)(W + (size_t)kc * OUT))[i];
        __syncthreads();
        #pragma unroll 2
        for (int k = 0; k < 32; k += 4) {
            float4 xv[R];
            #pragma unroll
            for (int r = 0; r < R; ++r) {
                xv[r] = *(const float4*)(X + (size_t)rows[r] * 128 + kc + k);
                if constexpr (FUSE_BN) {
                    float4 s4 = *(const float4*)&sc[kc + k];
                    float4 h4 = *(const float4*)&sh[kc + k];
                    xv[r].x = fmaxf(fmaf(xv[r].x, s4.x, h4.x), 0.f);
                    xv[r].y = fmaxf(fmaf(xv[r].y, s4.y, h4.y), 0.f);
                    xv[r].z = fmaxf(fmaf(xv[r].z, s4.z, h4.z), 0.f);
                    xv[r].w = fmaxf(fmaf(xv[r].w, s4.w, h4.w), 0.f);
                }
            }
            #pragma unroll
            for (int kk = 0; kk < 4; ++kk) {
                float4 w = *(const float4*)&sW[(k + kk) * OUT + cg * 4];
                #pragma unroll
                for (int r = 0; r < R; ++r) {
                    float xs = ((const float*)&xv[r])[kk];
                    acc[r][0] = fmaf(xs, w.x, acc[r][0]);
                    acc[r][1] = fmaf(xs, w.y, acc[r][1]);
                    acc[r][2] = fmaf(xs, w.z, acc[r][2]);
                    acc[r][3] = fmaf(xs, w.w, acc[r][3]);
                }
            }
        }
        __syncthreads();
    }
    #pragma unroll
    for (int r = 0; r < R; ++r)
        if (row0 + r < NN)
            *(float4*)&Y[(size_t)(row0 + r) * OUT + cg * 4] =
                make_float4(acc[r][0], acc[r][1], acc[r][2], acc[r][3]);
}

// ---------------- fused: CSR gather-aggregate + self-loop + bias + BN partial stats ----------------
template<int DIM>
__global__ __launch_bounds__(256) void agg_k(const int* __restrict__ rowptr,
                                             const int* __restrict__ esrc,
                                             const float* __restrict__ dis,
                                             const float* __restrict__ xw,
                                             const float* __restrict__ b,
                                             float* __restrict__ agg,
                                             float* __restrict__ sums,
                                             float* __restrict__ ssq) {
    const int lane = threadIdx.x & 63;
    const int wid = (blockIdx.x * 256 + threadIdx.x) >> 6;
    const int nwaves = gridDim.x * 4;
    float s0 = 0.f, s1 = 0.f, q0 = 0.f, q1 = 0.f;

    if constexpr (DIM == 128) {
        const float bc0 = b[lane * 2], bc1 = b[lane * 2 + 1];
        for (int n = wid; n < NN; n += nwaves) {
            const int beg = rowptr[n], end = rowptr[n + 1];
            const float dn = dis[n];
            float ax = 0.f, ay = 0.f;
            int e = beg;
            for (; e + 4 <= end; e += 4) {
                int i0 = esrc[e], i1 = esrc[e + 1], i2 = esrc[e + 2], i3 = esrc[e + 3];
                float w0 = dis[i0] * dn, w1 = dis[i1] * dn,
                      w2 = dis[i2] * dn, w3 = dis[i3] * dn;
                float2 v0 = *(const float2*)&xw[(size_t)i0 * 128 + lane * 2];
                float2 v1 = *(const float2*)&xw[(size_t)i1 * 128 + lane * 2];
                float2 v2 = *(const float2*)&xw[(size_t)i2 * 128 + lane * 2];
                float2 v3 = *(const float2*)&xw[(size_t)i3 * 128 + lane * 2];
                ax = fmaf(v0.x, w0, ax); ay = fmaf(v0.y, w0, ay);
                ax = fmaf(v1.x, w1, ax); ay = fmaf(v1.y, w1, ay);
                ax = fmaf(v2.x, w2, ax); ay = fmaf(v2.y, w2, ay);
                ax = fmaf(v3.x, w3, ax); ay = fmaf(v3.y, w3, ay);
            }
            for (; e < end; ++e) {
                int s = esrc[e];
                float w = dis[s] * dn;
                float2 v = *(const float2*)&xw[(size_t)s * 128 + lane * 2];
                ax = fmaf(v.x, w, ax); ay = fmaf(v.y, w, ay);
            }
            float sl = dn * dn;  // 1/(deg+1) self-loop norm
            float2 xv = *(const float2*)&xw[(size_t)n * 128 + lane * 2];
            ax = fmaf(xv.x, sl, ax) + bc0;
            ay = fmaf(xv.y, sl, ay) + bc1;
            *(float2*)&agg[(size_t)n * 128 + lane * 2] = make_float2(ax, ay);
            s0 += ax; q0 = fmaf(ax, ax, q0);
            s1 += ay; q1 = fmaf(ay, ay, q1);
        }
    } else {
        const float bc0 = b[lane];
        for (int n = wid; n < NN; n += nwaves) {
            const int beg = rowptr[n], end = rowptr[n + 1];
            const float dn = dis[n];
            float ax = 0.f;
            int e = beg;
            for (; e + 4 <= end; e += 4) {
                int i0 = esrc[e], i1 = esrc[e + 1], i2 = esrc[e + 2], i3 = esrc[e + 3];
                float w0 = dis[i0] * dn, w1 = dis[i1] * dn,
                      w2 = dis[i2] * dn, w3 = dis[i3] * dn;
                ax = fmaf(xw[(size_t)i0 * 64 + lane], w0, ax);
                ax = fmaf(xw[(size_t)i1 * 64 + lane], w1, ax);
                ax = fmaf(xw[(size_t)i2 * 64 + lane], w2, ax);
                ax = fmaf(xw[(size_t)i3 * 64 + lane], w3, ax);
            }
            for (; e < end; ++e) {
                int s = esrc[e];
                ax = fmaf(xw[(size_t)s * 64 + lane], dis[s] * dn, ax);
            }
            ax = fmaf(xw[(size_t)n * 64 + lane], dn * dn, ax) + bc0;
            agg[(size_t)n * 64 + lane] = ax;
            s0 += ax; q0 = fmaf(ax, ax, q0);
        }
    }

    __shared__ float ls[2 * DIM];
    if (threadIdx.x < 2 * DIM) ls[threadIdx.x] = 0.f;
    __syncthreads();
    if constexpr (DIM == 128) {
        atomicAdd(&ls[lane * 2], s0);
        atomicAdd(&ls[lane * 2 + 1], s1);
        atomicAdd(&ls[DIM + lane * 2], q0);
        atomicAdd(&ls[DIM + lane * 2 + 1], q1);
    } else {
        atomicAdd(&ls[lane], s0);
        atomicAdd(&ls[DIM + lane], q0);
    }
    __syncthreads();
    if (threadIdx.x < DIM) atomicAdd(&sums[threadIdx.x], ls[threadIdx.x]);
    else if (threadIdx.x < 2 * DIM) atomicAdd(&ssq[threadIdx.x - DIM], ls[threadIdx.x]);
}

// ---------------- final: out = relu(BN2(h2)) @ Wf + bf ----------------
__global__ __launch_bounds__(256) void final_k(const float* __restrict__ h,
                                               const float* __restrict__ coef,
                                               const float* __restrict__ Wf,
                                               const float* __restrict__ bf,
                                               float* __restrict__ out) {
    int wid = (blockIdx.x * 256 + threadIdx.x) >> 6;
    int lane = threadIdx.x & 63;
    if (wid >= NN) return;
    float v = fmaxf(fmaf(h[(size_t)wid * 64 + lane], coef[lane], coef[64 + lane]), 0.f)
              * Wf[lane];
    #pragma unroll
    for (int o = 32; o > 0; o >>= 1) v += __shfl_down(v, o);
    if (lane == 0) out[wid] = v + bf[0];
}

extern "C" void kernel_launch(void* const* d_in, const int* in_sizes, int n_in,
                              void* d_out, int out_size, void* d_ws, size_t ws_size,
                              hipStream_t stream) {
    const float* x   = (const float*)d_in[0];
    const int*   ei  = (const int*)d_in[1];
    const int*   src = ei;
    const int*   dst = ei + NE;
    const float* W1  = (const float*)d_in[2];
    const float* b1  = (const float*)d_in[3];
    const float* g1  = (const float*)d_in[4];
    const float* be1 = (const float*)d_in[5];
    const float* W2  = (const float*)d_in[6];
    const float* b2  = (const float*)d_in[7];
    const float* g2  = (const float*)d_in[8];
    const float* be2 = (const float*)d_in[9];
    const float* Wf  = (const float*)d_in[10];
    const float* bf  = (const float*)d_in[11];
    float* out = (float*)d_out;

    // ---- workspace layout ----
    float* xw    = (float*)d_ws;                 // NN*128 (reused as xw2)
    float* agg1  = xw    + (size_t)NN * D1;      // NN*128
    float* agg2  = agg1  + (size_t)NN * D1;      // NN*64
    float* dis   = agg2  + (size_t)NN * D2;      // NN
    float* sums1 = dis   + NN;                   // 128
    float* ssq1  = sums1 + D1;                   // 128
    float* sums2 = ssq1  + D1;                   // 64
    float* ssq2  = sums2 + D2;                   // 64
    float* coef1 = ssq2  + D2;                   // 256 (scale1,shift1)
    float* coef2 = coef1 + 2 * D1;               // 128 (scale2,shift2)
    int*   cnt    = (int*)(coef2 + 2 * D2);      // NN
    int*   cur    = cnt + NN;                    // NN
    int*   rowptr = cur + NN;                    // NN+1
    int*   bsum   = rowptr + NN + 1;             // 256 (pad)
    int*   esrc   = bsum + 256;                  // NE

    hipMemsetAsync(cnt, 0, sizeof(int) * 2 * NN, stream);
    hipMemsetAsync(sums1, 0, sizeof(float) * (2 * D1 + 2 * D2), stream);

    // ---- CSR build ----
    cnt_k<<<(NE + 255) / 256, 256, 0, stream>>>(dst, cnt);
    make_dis_k<<<(NN + 255) / 256, 256, 0, stream>>>(cnt, dis);
    scan1_k<<<NB_SCAN, SCAN_CHUNK, 0, stream>>>(cnt, rowptr, bsum);
    scan2_k<<<1, 64, 0, stream>>>(bsum);
    scan3_k<<<(NN + 255) / 256, 256, 0, stream>>>(rowptr, bsum);
    fill_k<<<(NE + 255) / 256, 256, 0, stream>>>(src, dst, rowptr, cur, esrc);

    // ---- layer 1 ----
    gemm_k<128, false><<<(NN + 63) / 64, 256, 0, stream>>>(x, W1, nullptr, xw);
    agg_k<128><<<1024, 256, 0, stream>>>(rowptr, esrc, dis, xw, b1, agg1, sums1, ssq1);
    bncoef_k<<<1, 128, 0, stream>>>(sums1, ssq1, g1, be1, coef1, D1);

    // ---- layer 2 (BN1+ReLU fused into GEMM input load) ----
    gemm_k<64, true><<<(NN + 63) / 64, 256, 0, stream>>>(agg1, W2, coef1, xw);
    agg_k<64><<<1024, 256, 0, stream>>>(rowptr, esrc, dis, xw, b2, agg2, sums2, ssq2);
    bncoef_k<<<1, 64, 0, stream>>>(sums2, ssq2, g2, be2, coef2, D2);

    // ---- final projection (BN2+ReLU fused) ----
    final_k<<<(NN * 64 + 255) / 256, 256, 0, stream>>>(agg2, coef2, Wf, bf, out);
}

// Round 4
// 533.868 us; speedup vs baseline: 4.3569x; 1.1058x over previous
//
#include <hip/hip_runtime.h>

#define NN 100000
#define NE 1600000
#define D1 128
#define D2 64
#define BN_EPS 1e-5f
#define SCAN_CHUNK 512
#define NB_SCAN ((NN + SCAN_CHUNK - 1) / SCAN_CHUNK)   // 196

typedef unsigned int uint32;
typedef unsigned short ushort16;

// ---- bf16 helpers (RNE) ----
__device__ __forceinline__ uint32 f2bf_pair(float a, float b) {
    uint32 ua = __float_as_uint(a), ub = __float_as_uint(b);
    ua = (ua + 0x7FFFu + ((ua >> 16) & 1u)) >> 16;
    ub = (ub + 0x7FFFu + ((ub >> 16) & 1u)) >> 16;
    return ua | (ub << 16);
}
__device__ __forceinline__ float bf_lo(uint32 v) { return __uint_as_float(v << 16); }
__device__ __forceinline__ float bf_hi(uint32 v) { return __uint_as_float(v & 0xFFFF0000u); }

// ---------------- degree count (int atomics, from dst) ----------------
__global__ __launch_bounds__(256) void cnt_k(const int* __restrict__ dst,
                                             int* __restrict__ cnt) {
    int i = blockIdx.x * 256 + threadIdx.x;
    if (i < NE) atomicAdd(&cnt[dst[i]], 1);
}

// ---------------- dis = rsqrt(cnt+1) ----------------
__global__ __launch_bounds__(256) void make_dis_k(const int* __restrict__ cnt,
                                                  float* __restrict__ dis) {
    int i = blockIdx.x * 256 + threadIdx.x;
    if (i < NN) dis[i] = rsqrtf((float)cnt[i] + 1.0f);
}

// ---------------- prefix scan (3 kernels) ----------------
__global__ __launch_bounds__(SCAN_CHUNK) void scan1_k(const int* __restrict__ cnt,
                                                      int* __restrict__ rowptr,
                                                      int* __restrict__ bsum) {
    __shared__ int sh[SCAN_CHUNK];
    int tid = threadIdx.x;
    int g = blockIdx.x * SCAN_CHUNK + tid;
    int v = (g < NN) ? cnt[g] : 0;
    sh[tid] = v;
    __syncthreads();
    for (int o = 1; o < SCAN_CHUNK; o <<= 1) {
        int t = (tid >= o) ? sh[tid - o] : 0;
        __syncthreads();
        sh[tid] += t;
        __syncthreads();
    }
    if (g < NN) rowptr[g] = sh[tid] - v;
    if (tid == SCAN_CHUNK - 1) bsum[blockIdx.x] = sh[tid];
}

__global__ void scan2_k(int* __restrict__ bsum) {
    if (threadIdx.x == 0 && blockIdx.x == 0) {
        int a = 0;
        for (int i = 0; i < NB_SCAN; ++i) { int t = bsum[i]; bsum[i] = a; a += t; }
    }
}

__global__ __launch_bounds__(256) void scan3_k(int* __restrict__ rowptr,
                                               const int* __restrict__ bsum) {
    int g = blockIdx.x * 256 + threadIdx.x;
    if (g < NN) rowptr[g] += bsum[g >> 9];
    if (g == 0) rowptr[NN] = NE;
}

// ---------------- CSR fill: slot-atomic per edge; also precompute edge weight ----------------
__global__ __launch_bounds__(256) void fill_k(const int* __restrict__ src,
                                              const int* __restrict__ dst,
                                              const int* __restrict__ rowptr,
                                              const float* __restrict__ dis,
                                              int* __restrict__ cur,
                                              int* __restrict__ esrc,
                                              float* __restrict__ ew) {
    int e = blockIdx.x * 256 + threadIdx.x;
    if (e >= NE) return;
    int d = dst[e];
    int s = src[e];
    int p = rowptr[d] + atomicAdd(&cur[d], 1);
    esrc[p] = s;
    ew[p] = dis[s] * dis[d];
}

// ---------------- BN coefficients ----------------
__global__ void bncoef_k(const float* __restrict__ sums, const float* __restrict__ ssq,
                         const float* __restrict__ g, const float* __restrict__ beta,
                         float* __restrict__ coef, int dim) {
    int c = threadIdx.x;
    if (c >= dim) return;
    float m = sums[c] * (1.0f / NN);
    float var = ssq[c] * (1.0f / NN) - m * m;
    float sc = g[c] * rsqrtf(var + BN_EPS);
    coef[c] = sc;
    coef[dim + c] = beta[c] - m * sc;
}

// ---------------- GEMM: Y[NN,OUT](bf16) = f(X)[NN,128] @ W[128,OUT] ----------------
template<int OUT, bool FUSE_BN>
__global__ __launch_bounds__(256, 3) void gemm_k(const float* __restrict__ X,
                                                 const float* __restrict__ W,
                                                 const float* __restrict__ coef,
                                                 uint32* __restrict__ Yb) {
    constexpr int CG = OUT / 4;      // col groups (32 or 16)
    constexpr int RG = 256 / CG;     // row groups (8 or 16)
    constexpr int R  = 64 / RG;      // rows/thread (8 or 4)
    __shared__ float sW[32 * OUT];
    __shared__ float sc[128], sh[128];
    if constexpr (FUSE_BN) {
        if (threadIdx.x < 128) {
            sc[threadIdx.x] = coef[threadIdx.x];
            sh[threadIdx.x] = coef[128 + threadIdx.x];
        }
    }
    const int cg = threadIdx.x % CG;
    const int rg = threadIdx.x / CG;
    const int row0 = blockIdx.x * 64 + rg * R;
    int rows[R];
    #pragma unroll
    for (int r = 0; r < R; ++r) rows[r] = min(row0 + r, NN - 1);
    float acc[R][4];
    #pragma unroll
    for (int r = 0; r < R; ++r)
        acc[r][0] = acc[r][1] = acc[r][2] = acc[r][3] = 0.f;

    for (int kc = 0; kc < 128; kc += 32) {
        for (int i = threadIdx.x; i < 32 * OUT / 4; i += 256)
            ((float4*)sW)[i] = ((const float4*)(W + (size_t)kc * OUT))[i];
        __syncthreads();
        #pragma unroll 2
        for (int k = 0; k < 32; k += 4) {
            float4 xv[R];
            #pragma unroll
            for (int r = 0; r < R; ++r) {
                xv[r] = *(const float4*)(X + (size_t)rows[r] * 128 + kc + k);
                if constexpr (FUSE_BN) {
                    float4 s4 = *(const float4*)&sc[kc + k];
                    float4 h4 = *(const float4*)&sh[kc + k];
                    xv[r].x = fmaxf(fmaf(xv[r].x, s4.x, h4.x), 0.f);
                    xv[r].y = fmaxf(fmaf(xv[r].y, s4.y, h4.y), 0.f);
                    xv[r].z = fmaxf(fmaf(xv[r].z, s4.z, h4.z), 0.f);
                    xv[r].w = fmaxf(fmaf(xv[r].w, s4.w, h4.w), 0.f);
                }
            }
            #pragma unroll
            for (int kk = 0; kk < 4; ++kk) {
                float4 w = *(const float4*)&sW[(k + kk) * OUT + cg * 4];
                #pragma unroll
                for (int r = 0; r < R; ++r) {
                    float xs = ((const float*)&xv[r])[kk];
                    acc[r][0] = fmaf(xs, w.x, acc[r][0]);
                    acc[r][1] = fmaf(xs, w.y, acc[r][1]);
                    acc[r][2] = fmaf(xs, w.z, acc[r][2]);
                    acc[r][3] = fmaf(xs, w.w, acc[r][3]);
                }
            }
        }
        __syncthreads();
    }
    #pragma unroll
    for (int r = 0; r < R; ++r)
        if (row0 + r < NN) {
            uint32 p0 = f2bf_pair(acc[r][0], acc[r][1]);
            uint32 p1 = f2bf_pair(acc[r][2], acc[r][3]);
            // Yb row has OUT/2 uint32 entries
            *(uint2*)&Yb[(size_t)(row0 + r) * (OUT / 2) + cg * 2] = make_uint2(p0, p1);
        }
}

// ---------------- fused: CSR gather-aggregate (bf16 xw) + self-loop + bias + BN stats ----------------
template<int DIM>
__global__ __launch_bounds__(256) void agg_k(const int* __restrict__ rowptr,
                                             const int* __restrict__ esrc,
                                             const float* __restrict__ ew,
                                             const float* __restrict__ dis,
                                             const uint32* __restrict__ xwb,  // bf16 pairs
                                             const float* __restrict__ b,
                                             float* __restrict__ agg,
                                             float* __restrict__ sums,
                                             float* __restrict__ ssq) {
    const int lane = threadIdx.x & 63;
    const int wid = (blockIdx.x * 256 + threadIdx.x) >> 6;
    const int nwaves = gridDim.x * 4;
    float s0 = 0.f, s1 = 0.f, q0 = 0.f, q1 = 0.f;

    if constexpr (DIM == 128) {
        const float bc0 = b[lane * 2], bc1 = b[lane * 2 + 1];
        for (int n = wid; n < NN; n += nwaves) {
            const int beg = rowptr[n], end = rowptr[n + 1];
            const float dn = dis[n];
            float ax = 0.f, ay = 0.f;
            int e = beg;
            for (; e + 8 <= end; e += 8) {
                int idx[8]; float w[8]; uint32 vv[8];
                #pragma unroll
                for (int j = 0; j < 8; ++j) idx[j] = esrc[e + j];
                #pragma unroll
                for (int j = 0; j < 8; ++j) w[j] = ew[e + j];
                #pragma unroll
                for (int j = 0; j < 8; ++j)
                    vv[j] = xwb[(size_t)idx[j] * 64 + lane];
                #pragma unroll
                for (int j = 0; j < 8; ++j) {
                    ax = fmaf(bf_lo(vv[j]), w[j], ax);
                    ay = fmaf(bf_hi(vv[j]), w[j], ay);
                }
            }
            for (; e < end; ++e) {
                int s = esrc[e];
                float w = ew[e];
                uint32 v = xwb[(size_t)s * 64 + lane];
                ax = fmaf(bf_lo(v), w, ax);
                ay = fmaf(bf_hi(v), w, ay);
            }
            float sl = dn * dn;  // 1/(deg+1) self-loop norm
            uint32 xv = xwb[(size_t)n * 64 + lane];
            ax = fmaf(bf_lo(xv), sl, ax) + bc0;
            ay = fmaf(bf_hi(xv), sl, ay) + bc1;
            *(float2*)&agg[(size_t)n * 128 + lane * 2] = make_float2(ax, ay);
            s0 += ax; q0 = fmaf(ax, ax, q0);
            s1 += ay; q1 = fmaf(ay, ay, q1);
        }
    } else {
        const ushort16* xws = (const ushort16*)xwb;
        const float bc0 = b[lane];
        for (int n = wid; n < NN; n += nwaves) {
            const int beg = rowptr[n], end = rowptr[n + 1];
            const float dn = dis[n];
            float ax = 0.f;
            int e = beg;
            for (; e + 8 <= end; e += 8) {
                int idx[8]; float w[8]; ushort16 vv[8];
                #pragma unroll
                for (int j = 0; j < 8; ++j) idx[j] = esrc[e + j];
                #pragma unroll
                for (int j = 0; j < 8; ++j) w[j] = ew[e + j];
                #pragma unroll
                for (int j = 0; j < 8; ++j)
                    vv[j] = xws[(size_t)idx[j] * 64 + lane];
                #pragma unroll
                for (int j = 0; j < 8; ++j)
                    ax = fmaf(__uint_as_float((uint32)vv[j] << 16), w[j], ax);
            }
            for (; e < end; ++e) {
                int s = esrc[e];
                ax = fmaf(__uint_as_float((uint32)xws[(size_t)s * 64 + lane] << 16),
                          ew[e], ax);
            }
            ax = fmaf(__uint_as_float((uint32)xws[(size_t)n * 64 + lane] << 16),
                      dn * dn, ax) + bc0;
            agg[(size_t)n * 64 + lane] = ax;
            s0 += ax; q0 = fmaf(ax, ax, q0);
        }
    }

    __shared__ float ls[2 * DIM];
    if (threadIdx.x < 2 * DIM) ls[threadIdx.x] = 0.f;
    __syncthreads();
    if constexpr (DIM == 128) {
        atomicAdd(&ls[lane * 2], s0);
        atomicAdd(&ls[lane * 2 + 1], s1);
        atomicAdd(&ls[DIM + lane * 2], q0);
        atomicAdd(&ls[DIM + lane * 2 + 1], q1);
    } else {
        atomicAdd(&ls[lane], s0);
        atomicAdd(&ls[DIM + lane], q0);
    }
    __syncthreads();
    if (threadIdx.x < DIM) atomicAdd(&sums[threadIdx.x], ls[threadIdx.x]);
    else if (threadIdx.x < 2 * DIM) atomicAdd(&ssq[threadIdx.x - DIM], ls[threadIdx.x]);
}

// ---------------- final: out = relu(BN2(h2)) @ Wf + bf ----------------
__global__ __launch_bounds__(256) void final_k(const float* __restrict__ h,
                                               const float* __restrict__ coef,
                                               const float* __restrict__ Wf,
                                               const float* __restrict__ bf,
                                               float* __restrict__ out) {
    int wid = (blockIdx.x * 256 + threadIdx.x) >> 6;
    int lane = threadIdx.x & 63;
    if (wid >= NN) return;
    float v = fmaxf(fmaf(h[(size_t)wid * 64 + lane], coef[lane], coef[64 + lane]), 0.f)
              * Wf[lane];
    #pragma unroll
    for (int o = 32; o > 0; o >>= 1) v += __shfl_down(v, o);
    if (lane == 0) out[wid] = v + bf[0];
}

extern "C" void kernel_launch(void* const* d_in, const int* in_sizes, int n_in,
                              void* d_out, int out_size, void* d_ws, size_t ws_size,
                              hipStream_t stream) {
    const float* x   = (const float*)d_in[0];
    const int*   ei  = (const int*)d_in[1];
    const int*   src = ei;
    const int*   dst = ei + NE;
    const float* W1  = (const float*)d_in[2];
    const float* b1  = (const float*)d_in[3];
    const float* g1  = (const float*)d_in[4];
    const float* be1 = (const float*)d_in[5];
    const float* W2  = (const float*)d_in[6];
    const float* b2  = (const float*)d_in[7];
    const float* g2  = (const float*)d_in[8];
    const float* be2 = (const float*)d_in[9];
    const float* Wf  = (const float*)d_in[10];
    const float* bf  = (const float*)d_in[11];
    float* out = (float*)d_out;

    // ---- workspace layout ----
    uint32* xwb  = (uint32*)d_ws;                      // NN*64 uint32 (bf16 pairs, 25.6MB)
    float* agg1  = (float*)(xwb + (size_t)NN * 64);    // NN*128 f32
    float* agg2  = agg1  + (size_t)NN * D1;            // NN*64 f32
    float* dis   = agg2  + (size_t)NN * D2;            // NN
    float* sums1 = dis   + NN;                         // 128
    float* ssq1  = sums1 + D1;
    float* sums2 = ssq1  + D1;
    float* ssq2  = sums2 + D2;
    float* coef1 = ssq2  + D2;                         // 256
    float* coef2 = coef1 + 2 * D1;                     // 128
    float* ew    = coef2 + 2 * D2;                     // NE
    int*   cnt    = (int*)(ew + NE);                   // NN
    int*   cur    = cnt + NN;                          // NN
    int*   rowptr = cur + NN;                          // NN+1
    int*   bsum   = rowptr + NN + 1;                   // 256 (pad)
    int*   esrc   = bsum + 256;                        // NE

    hipMemsetAsync(cnt, 0, sizeof(int) * 2 * NN, stream);
    hipMemsetAsync(sums1, 0, sizeof(float) * (2 * D1 + 2 * D2), stream);

    // ---- CSR build ----
    cnt_k<<<(NE + 255) / 256, 256, 0, stream>>>(dst, cnt);
    make_dis_k<<<(NN + 255) / 256, 256, 0, stream>>>(cnt, dis);
    scan1_k<<<NB_SCAN, SCAN_CHUNK, 0, stream>>>(cnt, rowptr, bsum);
    scan2_k<<<1, 64, 0, stream>>>(bsum);
    scan3_k<<<(NN + 255) / 256, 256, 0, stream>>>(rowptr, bsum);
    fill_k<<<(NE + 255) / 256, 256, 0, stream>>>(src, dst, rowptr, dis, cur, esrc, ew);

    // ---- layer 1 ----
    gemm_k<128, false><<<(NN + 63) / 64, 256, 0, stream>>>(x, W1, nullptr, xwb);
    agg_k<128><<<2048, 256, 0, stream>>>(rowptr, esrc, ew, dis, xwb, b1, agg1, sums1, ssq1);
    bncoef_k<<<1, 128, 0, stream>>>(sums1, ssq1, g1, be1, coef1, D1);

    // ---- layer 2 (BN1+ReLU fused into GEMM input load) ----
    gemm_k<64, true><<<(NN + 63) / 64, 256, 0, stream>>>(agg1, W2, coef1, xwb);
    agg_k<64><<<2048, 256, 0, stream>>>(rowptr, esrc, ew, dis, xwb, b2, agg2, sums2, ssq2);
    bncoef_k<<<1, 64, 0, stream>>>(sums2, ssq2, g2, be2, coef2, D2);

    // ---- final projection (BN2+ReLU fused) ----
    final_k<<<(NN * 64 + 255) / 256, 256, 0, stream>>>(agg2, coef2, Wf, bf, out);
}